// Round 9
// baseline (635.677 us; speedup 1.0000x reference)
//
#include <hip/hip_runtime.h>
#include <hip/hip_fp16.h>

#define N_NODES 100000
#define N_EDGES 1600000
#define NFEAT 128
#define NHID 64
#define N_GRAPHS 64
#define NLAYER 3
#define BN_EPS 1e-5f
#define POOL_SLICES 8
#define BW 512                                  // bucket node width
#define NBUCK ((N_NODES + BW - 1) / BW)         // 196
#define NBLK1 196                               // edge-chunk blocks
#define CH1 ((N_EDGES + NBLK1 - 1) / NBLK1)     // 8164

// ---------------------------------------------------------------- zero misc
__global__ void k_zero(float* __restrict__ stats, float* __restrict__ out) {
    int i = blockIdx.x * 256 + threadIdx.x;
    if (i < 4 * 128) stats[i] = 0.f;
    if (i < N_GRAPHS * NHID) out[i] = 0.f;
}

// ---------------------------------------- graph offsets via binary search
__global__ void k_offs(const int* __restrict__ batch, int* __restrict__ offs) {
    int t = threadIdx.x;
    if (t > N_GRAPHS) return;
    int lo = 0, hi = N_NODES;
    while (lo < hi) {
        int mid = (lo + hi) >> 1;
        if (batch[mid] < t) lo = mid + 1; else hi = mid;
    }
    offs[t] = lo;
}

// ----------------------------------- CSR build P1: per-(block,bucket) counts
__global__ __launch_bounds__(256) void k_bincount(const int* __restrict__ dst,
                                                  int* __restrict__ cnt) {
    __shared__ int h[NBUCK];
    int t = threadIdx.x, b = blockIdx.x;
    for (int i = t; i < NBUCK; i += 256) h[i] = 0;
    __syncthreads();
    int lo = b * CH1, hi = min(lo + CH1, N_EDGES);
    for (int e = lo + t; e < hi; e += 256) {
        int d = min(max(dst[e], 0), N_NODES - 1);
        atomicAdd(&h[d >> 9], 1);
    }
    __syncthreads();
    for (int i = t; i < NBUCK; i += 256) cnt[b * NBUCK + i] = h[i];
}

// ----------------------------------- CSR build P2: scan count matrix
__global__ __launch_bounds__(256) void k_binscan(int* __restrict__ cnt,
                                                 int* __restrict__ bbase,
                                                 int* __restrict__ row_start) {
    __shared__ int tot[NBUCK];
    int t = threadIdx.x;
    if (t < NBUCK) {
        int acc = 0;
        for (int blk = 0; blk < NBLK1; ++blk) {
            int idx = blk * NBUCK + t;
            int v = cnt[idx];
            cnt[idx] = acc;
            acc += v;
        }
        tot[t] = acc;
    }
    __syncthreads();
    if (t == 0) {
        int acc = 0;
        for (int i = 0; i < NBUCK; ++i) { bbase[i] = acc; acc += tot[i]; }
        bbase[NBUCK] = acc;
        row_start[N_NODES] = N_EDGES;
    }
}

// ----------------------------------- CSR build P3: stage edges by bucket
__global__ __launch_bounds__(256) void k_binstage(const int* __restrict__ src,
                                                  const int* __restrict__ dst,
                                                  const int* __restrict__ cnt,
                                                  const int* __restrict__ bbase,
                                                  int* __restrict__ stage) {
    __shared__ int cur[NBUCK];
    int t = threadIdx.x, b = blockIdx.x;
    for (int i = t; i < NBUCK; i += 256)
        cur[i] = bbase[i] + cnt[b * NBUCK + i];
    __syncthreads();
    int lo = b * CH1, hi = min(lo + CH1, N_EDGES);
    for (int e = lo + t; e < hi; e += 256) {
        int d = min(max(dst[e], 0), N_NODES - 1);
        int s = min(max(src[e], 0), N_NODES - 1);
        int bk = d >> 9;
        int slot = atomicAdd(&cur[bk], 1);
        stage[slot] = s | ((d & 511) << 17);
    }
}

// ----------------------------------- CSR build P4: per-bucket local sort
__global__ __launch_bounds__(256) void k_binbuild(const int* __restrict__ stage,
                                                  const int* __restrict__ bbase,
                                                  int* __restrict__ row_start,
                                                  int* __restrict__ esrc) {
    __shared__ int hist[BW];
    __shared__ int wsum2[4];
    int t = threadIdx.x, b = blockIdx.x;
    int base = bbase[b], end = bbase[b + 1];
    for (int i = t; i < BW; i += 256) hist[i] = 0;
    __syncthreads();
    for (int e = base + t; e < end; e += 256)
        atomicAdd(&hist[(unsigned)stage[e] >> 17], 1);
    __syncthreads();
    int a = hist[2 * t], c = hist[2 * t + 1];
    int p = a + c;
    int lane = t & 63, w = t >> 6;
    int incl = p;
    for (int off = 1; off < 64; off <<= 1) {
        int n = __shfl_up(incl, off);
        if (lane >= off) incl += n;
    }
    if (lane == 63) wsum2[w] = incl;
    __syncthreads();
    if (t < 4) {
        int s = wsum2[t], e2 = s;
        for (int off = 1; off < 4; off <<= 1) {
            int n = __shfl_up(e2, off, 4);
            if (t >= off) e2 += n;
        }
        wsum2[t] = e2 - s;
    }
    __syncthreads();
    int ex = incl - p + wsum2[w];
    hist[2 * t] = ex;
    hist[2 * t + 1] = ex + a;
    int g0 = b * BW + 2 * t;
    if (g0 < N_NODES) row_start[g0] = base + ex;
    if (g0 + 1 < N_NODES) row_start[g0 + 1] = base + ex + a;
    __syncthreads();
    for (int e = base + t; e < end; e += 256) {
        int v = stage[e];
        int ld = (unsigned)v >> 17, s = v & 0x1FFFF;
        int slot = atomicAdd(&hist[ld], 1);
        esrc[base + slot] = s;
    }
}

// ------------------------------------------------------------------- GEMM
// C[M,64] = act(A[M,K] @ W[K,64] + bias); ROWS=64 tile, K in 64-wide tiles.
// LDS 34 KB -> 4 blocks/CU (was 68 KB -> 2). Staging remapped so LDS writes
// are 2-way (free) instead of 16-way bank conflict (was 6.0M conflicts).
template <int K, bool RELU, bool STATS, bool HALF_OUT>
__global__ __launch_bounds__(256, 4) void k_gemm(const float* __restrict__ A,
                                                 const float* __restrict__ W,
                                                 const float* __restrict__ bias,
                                                 void* __restrict__ Cout,
                                                 float* __restrict__ stats, int M) {
    const int ROWS = 64, ROWP = 68, KT = 64, QT = KT / 4;
    __shared__ float At[KT * ROWP];   // transposed tile: At[k][r], 17408 B
    __shared__ float Ws[KT * NHID];   // 16384 B
    __shared__ float sblk[NHID], ssblk[NHID];
    int t = threadIdx.x;
    if (STATS && t < NHID) { sblk[t] = 0.f; ssblk[t] = 0.f; }
    int row0 = blockIdx.x * ROWS;
    int c0 = (t & 15) * 4;
    int r0 = (t >> 4) * 4;
    float acc[4][4];
#pragma unroll
    for (int i = 0; i < 4; ++i) {
        acc[i][0] = 0.f; acc[i][1] = 0.f; acc[i][2] = 0.f; acc[i][3] = 0.f;
    }

    for (int kt = 0; kt < K; kt += KT) {
        if (kt) __syncthreads();  // drain previous tile's FMA reads
        // stage W tile (linear float4 copy)
        for (int i = t; i < KT * NHID / 4; i += 256)
            ((float4*)Ws)[i] = ((const float4*)(W + (size_t)kt * NHID))[i];
        // stage A tile transposed; mapping keeps global 64B-coalesced and
        // LDS write banks at {r, r+16} (2 lanes/bank = conflict-free)
        for (int i = t; i < ROWS * QT; i += 256) {
            int qlo = i & 3, r = (i >> 2) & 63, qhi = i >> 8;
            int q = qlo + 4 * qhi;
            int gr = row0 + r;
            float4 v = make_float4(0.f, 0.f, 0.f, 0.f);
            if (gr < M) v = *(const float4*)(A + (size_t)gr * K + kt + 4 * q);
            At[(4 * q + 0) * ROWP + r] = v.x;
            At[(4 * q + 1) * ROWP + r] = v.y;
            At[(4 * q + 2) * ROWP + r] = v.z;
            At[(4 * q + 3) * ROWP + r] = v.w;
        }
        __syncthreads();

#pragma unroll 4
        for (int k = 0; k < KT; ++k) {
            float4 w = *(const float4*)&Ws[k * NHID + c0];
            float4 a = *(const float4*)&At[k * ROWP + r0];
            acc[0][0] = fmaf(a.x, w.x, acc[0][0]);
            acc[0][1] = fmaf(a.x, w.y, acc[0][1]);
            acc[0][2] = fmaf(a.x, w.z, acc[0][2]);
            acc[0][3] = fmaf(a.x, w.w, acc[0][3]);
            acc[1][0] = fmaf(a.y, w.x, acc[1][0]);
            acc[1][1] = fmaf(a.y, w.y, acc[1][1]);
            acc[1][2] = fmaf(a.y, w.z, acc[1][2]);
            acc[1][3] = fmaf(a.y, w.w, acc[1][3]);
            acc[2][0] = fmaf(a.z, w.x, acc[2][0]);
            acc[2][1] = fmaf(a.z, w.y, acc[2][1]);
            acc[2][2] = fmaf(a.z, w.z, acc[2][2]);
            acc[2][3] = fmaf(a.z, w.w, acc[2][3]);
            acc[3][0] = fmaf(a.w, w.x, acc[3][0]);
            acc[3][1] = fmaf(a.w, w.y, acc[3][1]);
            acc[3][2] = fmaf(a.w, w.z, acc[3][2]);
            acc[3][3] = fmaf(a.w, w.w, acc[3][3]);
        }
    }

    float4 b4 = *(const float4*)&bias[c0];
    float sp[4] = {0.f, 0.f, 0.f, 0.f};
    float ssp[4] = {0.f, 0.f, 0.f, 0.f};
#pragma unroll
    for (int i = 0; i < 4; ++i) {
        int gr = row0 + r0 + i;
        if (gr < M) {
            float4 v;
            v.x = acc[i][0] + b4.x;
            v.y = acc[i][1] + b4.y;
            v.z = acc[i][2] + b4.z;
            v.w = acc[i][3] + b4.w;
            if (RELU) {
                v.x = fmaxf(v.x, 0.f); v.y = fmaxf(v.y, 0.f);
                v.z = fmaxf(v.z, 0.f); v.w = fmaxf(v.w, 0.f);
            }
            if (HALF_OUT) {
                __half2* dst = (__half2*)((__half*)Cout + (size_t)gr * NHID + c0);
                dst[0] = __floats2half2_rn(v.x, v.y);
                dst[1] = __floats2half2_rn(v.z, v.w);
            } else {
                *(float4*)((float*)Cout + (size_t)gr * NHID + c0) = v;
            }
            if (STATS) {
                sp[0] += v.x; sp[1] += v.y; sp[2] += v.z; sp[3] += v.w;
                ssp[0] += v.x * v.x; ssp[1] += v.y * v.y;
                ssp[2] += v.z * v.z; ssp[3] += v.w * v.w;
            }
        }
    }

    if (STATS) {
#pragma unroll
        for (int j = 0; j < 4; ++j) {
            sp[j] += __shfl_down(sp[j], 32);
            sp[j] += __shfl_down(sp[j], 16);
            ssp[j] += __shfl_down(ssp[j], 32);
            ssp[j] += __shfl_down(ssp[j], 16);
        }
        if ((t & 63) < 16) {
#pragma unroll
            for (int j = 0; j < 4; ++j) {
                atomicAdd(&sblk[c0 + j], sp[j]);
                atomicAdd(&ssblk[c0 + j], ssp[j]);
            }
        }
        __syncthreads();
        if (t < NHID) {
            atomicAdd(&stats[t], sblk[t]);
            atomicAdd(&stats[NHID + t], ssblk[t]);
        }
    }
}

// --------------------------------------------- aggregation with folded BN
__global__ __launch_bounds__(256) void k_agg(const __half* __restrict__ y,
                                             const int* __restrict__ row_start,
                                             const int* __restrict__ esrc,
                                             const float* __restrict__ stats,
                                             const float* __restrict__ gamma,
                                             const float* __restrict__ beta,
                                             float* __restrict__ z) {
    int w = (blockIdx.x * 256 + threadIdx.x) >> 5;
    int l = threadIdx.x & 31;
    if (w >= N_NODES) return;
    const float invN = 1.0f / (float)N_NODES;
    float m0 = stats[2 * l] * invN,     q0 = stats[NHID + 2 * l] * invN;
    float m1 = stats[2 * l + 1] * invN, q1 = stats[NHID + 2 * l + 1] * invN;
    float i0 = rsqrtf(q0 - m0 * m0 + BN_EPS);
    float i1 = rsqrtf(q1 - m1 * m1 + BN_EPS);
    float g0 = gamma[2 * l], g1 = gamma[2 * l + 1];
    float a0 = g0 * i0, a1 = g1 * i1;
    float c0 = beta[2 * l] - g0 * m0 * i0;
    float c1 = beta[2 * l + 1] - g1 * m1 * i1;

    int s = row_start[w], e = row_start[w + 1];
    float2 acc = __half22float2(((const __half2*)(y + (size_t)w * NHID))[l]);
    int i = s;
    for (; i + 1 < e; i += 2) {
        int s0 = esrc[i], s1 = esrc[i + 1];
        float2 v0 = __half22float2(((const __half2*)(y + (size_t)s0 * NHID))[l]);
        float2 v1 = __half22float2(((const __half2*)(y + (size_t)s1 * NHID))[l]);
        acc.x += v0.x; acc.y += v0.y;
        acc.x += v1.x; acc.y += v1.y;
    }
    if (i < e) {
        float2 v = __half22float2(((const __half2*)(y + (size_t)esrc[i] * NHID))[l]);
        acc.x += v.x; acc.y += v.y;
    }
    float k = (float)(1 + e - s);
    float2 zo;
    zo.x = fmaf(a0, acc.x, k * c0);
    zo.y = fmaf(a1, acc.y, k * c1);
    *(float2*)(z + (size_t)w * NHID + 2 * l) = zo;
}

// -------------------------------------- mean pooling with folded BN affine
__global__ void k_pool(const __half* __restrict__ y, const int* __restrict__ offs,
                       const float* __restrict__ stats,
                       const float* __restrict__ gamma,
                       const float* __restrict__ beta,
                       float* __restrict__ out) {
    int g = blockIdx.x & 63;
    int slice = blockIdx.x >> 6;
    int s = offs[g], e = offs[g + 1];
    int f = threadIdx.x & 31;
    int j = threadIdx.x >> 5;
    float2 acc = make_float2(0.f, 0.f);
    for (int n = s + j + slice * 8; n < e; n += 8 * POOL_SLICES) {
        float2 v = __half22float2(((const __half2*)(y + (size_t)n * NHID))[f]);
        acc.x += v.x; acc.y += v.y;
    }
    __shared__ float2 red[8][32];
    red[j][f] = acc;
    __syncthreads();
    if (threadIdx.x < 32) {
        float2 t = make_float2(0.f, 0.f);
#pragma unroll
        for (int r = 0; r < 8; ++r) { t.x += red[r][f].x; t.y += red[r][f].y; }
        int cnt = e - s;
        if (cnt > 0) {
            const float invN = 1.0f / (float)N_NODES;
            float m0 = stats[2 * f] * invN,     q0 = stats[NHID + 2 * f] * invN;
            float m1 = stats[2 * f + 1] * invN, q1 = stats[NHID + 2 * f + 1] * invN;
            float i0 = rsqrtf(q0 - m0 * m0 + BN_EPS);
            float i1 = rsqrtf(q1 - m1 * m1 + BN_EPS);
            float g0 = gamma[2 * f], g1 = gamma[2 * f + 1];
            float a0 = g0 * i0, a1 = g1 * i1;
            float c0 = beta[2 * f] - g0 * m0 * i0;
            float c1 = beta[2 * f + 1] - g1 * m1 * i1;
            float inv = 1.0f / (float)cnt;
            float add0 = a0 * t.x * inv + (slice == 0 ? c0 : 0.f);
            float add1 = a1 * t.y * inv + (slice == 0 ? c1 : 0.f);
            atomicAdd(&out[g * NHID + 2 * f], add0);
            atomicAdd(&out[g * NHID + 2 * f + 1], add1);
        }
    }
}

// ------------------------------------------------------------------- host
extern "C" void kernel_launch(void* const* d_in, const int* in_sizes, int n_in,
                              void* d_out, int out_size, void* d_ws, size_t ws_size,
                              hipStream_t stream) {
    const float* x     = (const float*)d_in[0];
    const int*   ei    = (const int*)d_in[1];
    const int*   batch = (const int*)d_in[2];
    const float* W_t   = (const float*)d_in[3];
    const float* b_t   = (const float*)d_in[4];
    const float* bn0_g = (const float*)d_in[5];
    const float* bn0_b = (const float*)d_in[6];
    const float* W1    = (const float*)d_in[7];
    const float* b1    = (const float*)d_in[8];
    const float* W2    = (const float*)d_in[9];
    const float* b2    = (const float*)d_in[10];
    const float* bng   = (const float*)d_in[11];
    const float* bnb   = (const float*)d_in[12];
    float* out = (float*)d_out;

    const size_t NM = (size_t)N_NODES * NHID;
    const size_t need_bytes =
        (2 * NM + 4 * 128) * sizeof(float) +
        NM * sizeof(__half) +
        (size_t)((N_GRAPHS + 1) + (N_NODES + 1) + N_EDGES + N_EDGES +
                 NBLK1 * NBUCK + (NBUCK + 1)) * sizeof(int);
    if (ws_size < need_bytes) return;

    float* zbuf  = (float*)d_ws;
    float* cbuf  = zbuf + NM;
    float* stats = cbuf + NM;
    __half* y    = (__half*)(stats + 4 * 128);
    int* offs      = (int*)(y + NM);
    int* row_start = offs + N_GRAPHS + 1;
    int* esrc      = row_start + N_NODES + 1;
    int* stage     = esrc + N_EDGES;
    int* cnt       = stage + N_EDGES;
    int* bbase     = cnt + NBLK1 * NBUCK;

    const int* src = ei;
    const int* dst = ei + N_EDGES;

    // --- setup: zero, offsets, atomic-free binned CSR build ---
    k_zero<<<(N_GRAPHS * NHID + 255) / 256, 256, 0, stream>>>(stats, out);
    k_offs<<<1, 128, 0, stream>>>(batch, offs);
    k_bincount<<<NBLK1, 256, 0, stream>>>(dst, cnt);
    k_binscan<<<1, 256, 0, stream>>>(cnt, bbase, row_start);
    k_binstage<<<NBLK1, 256, 0, stream>>>(src, dst, cnt, bbase, stage);
    k_binbuild<<<NBUCK, 256, 0, stream>>>(stage, bbase, row_start, esrc);

    // --- transform: y0 = x @ W_t + b_t (stats stage 0), BN folded downstream
    k_gemm<NFEAT, false, true, true>
        <<<(N_NODES + 63) / 64, 256, 0, stream>>>(x, W_t, b_t, y, stats, N_NODES);
    k_pool<<<64 * POOL_SLICES, 256, 0, stream>>>(y, offs, stats, bn0_g, bn0_b, out);

    // --- GIN layers ---
    for (int i = 0; i < NLAYER; ++i) {
        const float* sg = (i == 0) ? bn0_g : bng + (i - 1) * NHID;
        const float* sb = (i == 0) ? bn0_b : bnb + (i - 1) * NHID;
        k_agg<<<(N_NODES * 32 + 255) / 256, 256, 0, stream>>>(
            y, row_start, esrc, stats + i * 128, sg, sb, zbuf);
        k_gemm<NHID, true, false, false>
            <<<(N_NODES + 63) / 64, 256, 0, stream>>>(zbuf, W1 + i * NHID * NHID,
                                                      b1 + i * NHID, cbuf, nullptr,
                                                      N_NODES);
        k_gemm<NHID, true, true, true>
            <<<(N_NODES + 63) / 64, 256, 0, stream>>>(cbuf, W2 + i * NHID * NHID,
                                                      b2 + i * NHID, y,
                                                      stats + (1 + i) * 128, N_NODES);
        k_pool<<<64 * POOL_SLICES, 256, 0, stream>>>(y, offs, stats + (1 + i) * 128,
                                                     bng + i * NHID, bnb + i * NHID, out);
    }
}

// Round 10
// 601.206 us; speedup vs baseline: 1.0573x; 1.0573x over previous
//
#include <hip/hip_runtime.h>
#include <hip/hip_fp16.h>

#define N_NODES 100000
#define N_EDGES 1600000
#define NFEAT 128
#define NHID 64
#define N_GRAPHS 64
#define NLAYER 3
#define BN_EPS 1e-5f
#define POOL_SLICES 8
#define BW 512
#define NBUCK ((N_NODES + BW - 1) / BW)         // 196
#define NBLK1 196
#define CH1 ((N_EDGES + NBLK1 - 1) / NBLK1)     // 8164

// ---------------------------------------------------------------- zero misc
__global__ void k_zero(float* __restrict__ stats, float* __restrict__ out) {
    int i = blockIdx.x * 256 + threadIdx.x;
    if (i < 4 * 128) stats[i] = 0.f;
    if (i < N_GRAPHS * NHID) out[i] = 0.f;
}

// ---------------------------------------- graph offsets via binary search
__global__ void k_offs(const int* __restrict__ batch, int* __restrict__ offs) {
    int t = threadIdx.x;
    if (t > N_GRAPHS) return;
    int lo = 0, hi = N_NODES;
    while (lo < hi) {
        int mid = (lo + hi) >> 1;
        if (batch[mid] < t) lo = mid + 1; else hi = mid;
    }
    offs[t] = lo;
}

// ----------------------------------- CSR build P1: per-(block,bucket) counts
__global__ __launch_bounds__(256) void k_bincount(const int* __restrict__ dst,
                                                  int* __restrict__ cnt) {
    __shared__ int h[NBUCK];
    int t = threadIdx.x, b = blockIdx.x;
    for (int i = t; i < NBUCK; i += 256) h[i] = 0;
    __syncthreads();
    int lo = b * CH1, hi = min(lo + CH1, N_EDGES);
    for (int e = lo + t; e < hi; e += 256) {
        int d = min(max(dst[e], 0), N_NODES - 1);
        atomicAdd(&h[d >> 9], 1);
    }
    __syncthreads();
    for (int i = t; i < NBUCK; i += 256) cnt[b * NBUCK + i] = h[i];
}

// ----------------------------------- CSR build P2: scan count matrix
__global__ __launch_bounds__(256) void k_binscan(int* __restrict__ cnt,
                                                 int* __restrict__ bbase,
                                                 int* __restrict__ row_start) {
    __shared__ int tot[NBUCK];
    int t = threadIdx.x;
    if (t < NBUCK) {
        int acc = 0;
        for (int blk = 0; blk < NBLK1; ++blk) {
            int idx = blk * NBUCK + t;
            int v = cnt[idx];
            cnt[idx] = acc;
            acc += v;
        }
        tot[t] = acc;
    }
    __syncthreads();
    if (t == 0) {
        int acc = 0;
        for (int i = 0; i < NBUCK; ++i) { bbase[i] = acc; acc += tot[i]; }
        bbase[NBUCK] = acc;
        row_start[N_NODES] = N_EDGES;
    }
}

// ----------------------------------- CSR build P3: stage edges by bucket
__global__ __launch_bounds__(256) void k_binstage(const int* __restrict__ src,
                                                  const int* __restrict__ dst,
                                                  const int* __restrict__ cnt,
                                                  const int* __restrict__ bbase,
                                                  int* __restrict__ stage) {
    __shared__ int cur[NBUCK];
    int t = threadIdx.x, b = blockIdx.x;
    for (int i = t; i < NBUCK; i += 256)
        cur[i] = bbase[i] + cnt[b * NBUCK + i];
    __syncthreads();
    int lo = b * CH1, hi = min(lo + CH1, N_EDGES);
    for (int e = lo + t; e < hi; e += 256) {
        int d = min(max(dst[e], 0), N_NODES - 1);
        int s = min(max(src[e], 0), N_NODES - 1);
        int bk = d >> 9;
        int slot = atomicAdd(&cur[bk], 1);
        stage[slot] = s | ((d & 511) << 17);
    }
}

// ----------------------------------- CSR build P4: per-bucket local sort
__global__ __launch_bounds__(256) void k_binbuild(const int* __restrict__ stage,
                                                  const int* __restrict__ bbase,
                                                  int* __restrict__ row_start,
                                                  int* __restrict__ esrc) {
    __shared__ int hist[BW];
    __shared__ int wsum2[4];
    int t = threadIdx.x, b = blockIdx.x;
    int base = bbase[b], end = bbase[b + 1];
    for (int i = t; i < BW; i += 256) hist[i] = 0;
    __syncthreads();
    for (int e = base + t; e < end; e += 256)
        atomicAdd(&hist[(unsigned)stage[e] >> 17], 1);
    __syncthreads();
    int a = hist[2 * t], c = hist[2 * t + 1];
    int p = a + c;
    int lane = t & 63, w = t >> 6;
    int incl = p;
    for (int off = 1; off < 64; off <<= 1) {
        int n = __shfl_up(incl, off);
        if (lane >= off) incl += n;
    }
    if (lane == 63) wsum2[w] = incl;
    __syncthreads();
    if (t < 4) {
        int s = wsum2[t], e2 = s;
        for (int off = 1; off < 4; off <<= 1) {
            int n = __shfl_up(e2, off, 4);
            if (t >= off) e2 += n;
        }
        wsum2[t] = e2 - s;
    }
    __syncthreads();
    int ex = incl - p + wsum2[w];
    hist[2 * t] = ex;
    hist[2 * t + 1] = ex + a;
    int g0 = b * BW + 2 * t;
    if (g0 < N_NODES) row_start[g0] = base + ex;
    if (g0 + 1 < N_NODES) row_start[g0 + 1] = base + ex + a;
    __syncthreads();
    for (int e = base + t; e < end; e += 256) {
        int v = stage[e];
        int ld = (unsigned)v >> 17, s = v & 0x1FFFF;
        int slot = atomicAdd(&hist[ld], 1);
        esrc[base + slot] = s;
    }
}

// ------------------------------------------------- transform GEMM (K=128)
// y = fp16(x @ W_t + b_t), fused column stats. No A-staging: lanes 0-15
// share a row -> broadcast loads, 64x512B tile is L1-resident. W in LDS.
__global__ __launch_bounds__(256, 4) void k_xform(const float* __restrict__ A,
                                                  const float* __restrict__ W,
                                                  const float* __restrict__ bias,
                                                  __half* __restrict__ y,
                                                  float* __restrict__ stats, int M) {
    __shared__ float Ws[NFEAT * NHID];   // 32 KB
    __shared__ float sblk[NHID], ssblk[NHID];
    int t = threadIdx.x;
    if (t < NHID) { sblk[t] = 0.f; ssblk[t] = 0.f; }
    for (int i = t; i < NFEAT * NHID / 4; i += 256)
        ((float4*)Ws)[i] = ((const float4*)W)[i];
    __syncthreads();

    int row0 = blockIdx.x * 64;
    int c0 = (t & 15) * 4, r0 = (t >> 4) * 4;
    const float* ar[4];
#pragma unroll
    for (int i = 0; i < 4; ++i)
        ar[i] = A + (size_t)min(row0 + r0 + i, M - 1) * NFEAT;

    float acc[4][4];
#pragma unroll
    for (int i = 0; i < 4; ++i)
        { acc[i][0]=0.f; acc[i][1]=0.f; acc[i][2]=0.f; acc[i][3]=0.f; }

#pragma unroll 2
    for (int k4 = 0; k4 < NFEAT / 4; ++k4) {
        float4 a[4];
#pragma unroll
        for (int i = 0; i < 4; ++i) a[i] = *(const float4*)(ar[i] + 4 * k4);
#pragma unroll
        for (int kk = 0; kk < 4; ++kk) {
            float4 wv = *(const float4*)&Ws[(4 * k4 + kk) * NHID + c0];
#pragma unroll
            for (int i = 0; i < 4; ++i) {
                float av = ((const float*)&a[i])[kk];
                acc[i][0] = fmaf(av, wv.x, acc[i][0]);
                acc[i][1] = fmaf(av, wv.y, acc[i][1]);
                acc[i][2] = fmaf(av, wv.z, acc[i][2]);
                acc[i][3] = fmaf(av, wv.w, acc[i][3]);
            }
        }
    }

    float4 b4 = *(const float4*)&bias[c0];
    float sp[4] = {0.f, 0.f, 0.f, 0.f};
    float ssp[4] = {0.f, 0.f, 0.f, 0.f};
#pragma unroll
    for (int i = 0; i < 4; ++i) {
        int gr = row0 + r0 + i;
        if (gr < M) {
            float vx = acc[i][0] + b4.x, vy = acc[i][1] + b4.y;
            float vz = acc[i][2] + b4.z, vw = acc[i][3] + b4.w;
            __half2* dsty = (__half2*)(y + (size_t)gr * NHID + c0);
            dsty[0] = __floats2half2_rn(vx, vy);
            dsty[1] = __floats2half2_rn(vz, vw);
            sp[0] += vx; sp[1] += vy; sp[2] += vz; sp[3] += vw;
            ssp[0] += vx * vx; ssp[1] += vy * vy;
            ssp[2] += vz * vz; ssp[3] += vw * vw;
        }
    }
#pragma unroll
    for (int j = 0; j < 4; ++j) {
        sp[j] += __shfl_down(sp[j], 32);
        sp[j] += __shfl_down(sp[j], 16);
        ssp[j] += __shfl_down(ssp[j], 32);
        ssp[j] += __shfl_down(ssp[j], 16);
    }
    if ((t & 63) < 16) {
#pragma unroll
        for (int j = 0; j < 4; ++j) {
            atomicAdd(&sblk[c0 + j], sp[j]);
            atomicAdd(&ssblk[c0 + j], ssp[j]);
        }
    }
    __syncthreads();
    if (t < NHID) {
        atomicAdd(&stats[t], sblk[t]);
        atomicAdd(&stats[NHID + t], ssblk[t]);
    }
}

// ---------------------------------------------- fused layer MLP (2 GEMMs)
// y = fp16(relu(relu(z @ W1 + b1) @ W2 + b2)), fused stats. c1 tile in LDS.
__global__ __launch_bounds__(256, 4) void k_layer(const __half* __restrict__ z,
                                                  const float* __restrict__ W1,
                                                  const float* __restrict__ b1,
                                                  const float* __restrict__ W2,
                                                  const float* __restrict__ b2,
                                                  __half* __restrict__ y,
                                                  float* __restrict__ stats, int M) {
    __shared__ float Ws[NHID * NHID];    // 16 KB, W1 then W2
    __shared__ float c1t[64 * 68];       // 17.4 KB, 2-way banks (free)
    __shared__ float sblk[NHID], ssblk[NHID];
    int t = threadIdx.x;
    if (t < NHID) { sblk[t] = 0.f; ssblk[t] = 0.f; }
    for (int i = t; i < NHID * NHID / 4; i += 256)
        ((float4*)Ws)[i] = ((const float4*)W1)[i];
    __syncthreads();

    int row0 = blockIdx.x * 64;
    int c0 = (t & 15) * 4, r0 = (t >> 4) * 4;
    const __half* zr[4];
#pragma unroll
    for (int i = 0; i < 4; ++i)
        zr[i] = z + (size_t)min(row0 + r0 + i, M - 1) * NHID;

    float acc[4][4];
#pragma unroll
    for (int i = 0; i < 4; ++i)
        { acc[i][0]=0.f; acc[i][1]=0.f; acc[i][2]=0.f; acc[i][3]=0.f; }

    // ---- GEMM1: c1 = relu(z @ W1 + b1)
#pragma unroll 2
    for (int k4 = 0; k4 < NHID / 4; ++k4) {
        float4 a[4];
#pragma unroll
        for (int i = 0; i < 4; ++i) {
            float2 f0 = __half22float2(((const __half2*)zr[i])[2 * k4]);
            float2 f1 = __half22float2(((const __half2*)zr[i])[2 * k4 + 1]);
            a[i] = make_float4(f0.x, f0.y, f1.x, f1.y);
        }
#pragma unroll
        for (int kk = 0; kk < 4; ++kk) {
            float4 wv = *(const float4*)&Ws[(4 * k4 + kk) * NHID + c0];
#pragma unroll
            for (int i = 0; i < 4; ++i) {
                float av = ((const float*)&a[i])[kk];
                acc[i][0] = fmaf(av, wv.x, acc[i][0]);
                acc[i][1] = fmaf(av, wv.y, acc[i][1]);
                acc[i][2] = fmaf(av, wv.z, acc[i][2]);
                acc[i][3] = fmaf(av, wv.w, acc[i][3]);
            }
        }
    }
    __syncthreads();   // all Ws(W1) reads done
    {
        float4 bb = *(const float4*)&b1[c0];
#pragma unroll
        for (int i = 0; i < 4; ++i) {
            float4 v;
            v.x = fmaxf(acc[i][0] + bb.x, 0.f);
            v.y = fmaxf(acc[i][1] + bb.y, 0.f);
            v.z = fmaxf(acc[i][2] + bb.z, 0.f);
            v.w = fmaxf(acc[i][3] + bb.w, 0.f);
            *(float4*)&c1t[(r0 + i) * 68 + c0] = v;
            acc[i][0] = 0.f; acc[i][1] = 0.f; acc[i][2] = 0.f; acc[i][3] = 0.f;
        }
    }
    for (int i = t; i < NHID * NHID / 4; i += 256)
        ((float4*)Ws)[i] = ((const float4*)W2)[i];
    __syncthreads();

    // ---- GEMM2: y = relu(c1 @ W2 + b2)
#pragma unroll 2
    for (int k4 = 0; k4 < NHID / 4; ++k4) {
        float4 a[4];
#pragma unroll
        for (int i = 0; i < 4; ++i)
            a[i] = *(const float4*)&c1t[(r0 + i) * 68 + 4 * k4];
#pragma unroll
        for (int kk = 0; kk < 4; ++kk) {
            float4 wv = *(const float4*)&Ws[(4 * k4 + kk) * NHID + c0];
#pragma unroll
            for (int i = 0; i < 4; ++i) {
                float av = ((const float*)&a[i])[kk];
                acc[i][0] = fmaf(av, wv.x, acc[i][0]);
                acc[i][1] = fmaf(av, wv.y, acc[i][1]);
                acc[i][2] = fmaf(av, wv.z, acc[i][2]);
                acc[i][3] = fmaf(av, wv.w, acc[i][3]);
            }
        }
    }

    float4 b4 = *(const float4*)&b2[c0];
    float sp[4] = {0.f, 0.f, 0.f, 0.f};
    float ssp[4] = {0.f, 0.f, 0.f, 0.f};
#pragma unroll
    for (int i = 0; i < 4; ++i) {
        int gr = row0 + r0 + i;
        if (gr < M) {
            float vx = fmaxf(acc[i][0] + b4.x, 0.f);
            float vy = fmaxf(acc[i][1] + b4.y, 0.f);
            float vz = fmaxf(acc[i][2] + b4.z, 0.f);
            float vw = fmaxf(acc[i][3] + b4.w, 0.f);
            __half2* dsty = (__half2*)(y + (size_t)gr * NHID + c0);
            dsty[0] = __floats2half2_rn(vx, vy);
            dsty[1] = __floats2half2_rn(vz, vw);
            sp[0] += vx; sp[1] += vy; sp[2] += vz; sp[3] += vw;
            ssp[0] += vx * vx; ssp[1] += vy * vy;
            ssp[2] += vz * vz; ssp[3] += vw * vw;
        }
    }
#pragma unroll
    for (int j = 0; j < 4; ++j) {
        sp[j] += __shfl_down(sp[j], 32);
        sp[j] += __shfl_down(sp[j], 16);
        ssp[j] += __shfl_down(ssp[j], 32);
        ssp[j] += __shfl_down(ssp[j], 16);
    }
    if ((t & 63) < 16) {
#pragma unroll
        for (int j = 0; j < 4; ++j) {
            atomicAdd(&sblk[c0 + j], sp[j]);
            atomicAdd(&ssblk[c0 + j], ssp[j]);
        }
    }
    __syncthreads();
    if (t < NHID) {
        atomicAdd(&stats[t], sblk[t]);
        atomicAdd(&stats[NHID + t], ssblk[t]);
    }
}

// --------------------------------------------- aggregation with folded BN
// z_i = fp16( a ∘ (y_i + Σ_{j∈N(i)} y_j) + (1+deg_i)·c )
__global__ __launch_bounds__(256) void k_agg(const __half* __restrict__ y,
                                             const int* __restrict__ row_start,
                                             const int* __restrict__ esrc,
                                             const float* __restrict__ stats,
                                             const float* __restrict__ gamma,
                                             const float* __restrict__ beta,
                                             __half* __restrict__ z) {
    int w = (blockIdx.x * 256 + threadIdx.x) >> 5;
    int l = threadIdx.x & 31;
    if (w >= N_NODES) return;
    const float invN = 1.0f / (float)N_NODES;
    float m0 = stats[2 * l] * invN,     q0 = stats[NHID + 2 * l] * invN;
    float m1 = stats[2 * l + 1] * invN, q1 = stats[NHID + 2 * l + 1] * invN;
    float i0 = rsqrtf(q0 - m0 * m0 + BN_EPS);
    float i1 = rsqrtf(q1 - m1 * m1 + BN_EPS);
    float g0 = gamma[2 * l], g1 = gamma[2 * l + 1];
    float a0 = g0 * i0, a1 = g1 * i1;
    float c0 = beta[2 * l] - g0 * m0 * i0;
    float c1 = beta[2 * l + 1] - g1 * m1 * i1;

    int s = row_start[w], e = row_start[w + 1];
    float2 acc = __half22float2(((const __half2*)(y + (size_t)w * NHID))[l]);
    int i = s;
    for (; i + 1 < e; i += 2) {
        int s0 = esrc[i], s1 = esrc[i + 1];
        float2 v0 = __half22float2(((const __half2*)(y + (size_t)s0 * NHID))[l]);
        float2 v1 = __half22float2(((const __half2*)(y + (size_t)s1 * NHID))[l]);
        acc.x += v0.x; acc.y += v0.y;
        acc.x += v1.x; acc.y += v1.y;
    }
    if (i < e) {
        float2 v = __half22float2(((const __half2*)(y + (size_t)esrc[i] * NHID))[l]);
        acc.x += v.x; acc.y += v.y;
    }
    float k = (float)(1 + e - s);
    ((__half2*)(z + (size_t)w * NHID))[l] =
        __floats2half2_rn(fmaf(a0, acc.x, k * c0), fmaf(a1, acc.y, k * c1));
}

// -------------------------------------- mean pooling with folded BN affine
__global__ void k_pool(const __half* __restrict__ y, const int* __restrict__ offs,
                       const float* __restrict__ stats,
                       const float* __restrict__ gamma,
                       const float* __restrict__ beta,
                       float* __restrict__ out) {
    int g = blockIdx.x & 63;
    int slice = blockIdx.x >> 6;
    int s = offs[g], e = offs[g + 1];
    int f = threadIdx.x & 31;
    int j = threadIdx.x >> 5;
    float2 acc = make_float2(0.f, 0.f);
    for (int n = s + j + slice * 8; n < e; n += 8 * POOL_SLICES) {
        float2 v = __half22float2(((const __half2*)(y + (size_t)n * NHID))[f]);
        acc.x += v.x; acc.y += v.y;
    }
    __shared__ float2 red[8][32];
    red[j][f] = acc;
    __syncthreads();
    if (threadIdx.x < 32) {
        float2 t = make_float2(0.f, 0.f);
#pragma unroll
        for (int r = 0; r < 8; ++r) { t.x += red[r][f].x; t.y += red[r][f].y; }
        int cnt = e - s;
        if (cnt > 0) {
            const float invN = 1.0f / (float)N_NODES;
            float m0 = stats[2 * f] * invN,     q0 = stats[NHID + 2 * f] * invN;
            float m1 = stats[2 * f + 1] * invN, q1 = stats[NHID + 2 * f + 1] * invN;
            float i0 = rsqrtf(q0 - m0 * m0 + BN_EPS);
            float i1 = rsqrtf(q1 - m1 * m1 + BN_EPS);
            float g0 = gamma[2 * f], g1 = gamma[2 * f + 1];
            float a0 = g0 * i0, a1 = g1 * i1;
            float c0 = beta[2 * f] - g0 * m0 * i0;
            float c1 = beta[2 * f + 1] - g1 * m1 * i1;
            float inv = 1.0f / (float)cnt;
            float add0 = a0 * t.x * inv + (slice == 0 ? c0 : 0.f);
            float add1 = a1 * t.y * inv + (slice == 0 ? c1 : 0.f);
            atomicAdd(&out[g * NHID + 2 * f], add0);
            atomicAdd(&out[g * NHID + 2 * f + 1], add1);
        }
    }
}

// ------------------------------------------------------------------- host
extern "C" void kernel_launch(void* const* d_in, const int* in_sizes, int n_in,
                              void* d_out, int out_size, void* d_ws, size_t ws_size,
                              hipStream_t stream) {
    const float* x     = (const float*)d_in[0];
    const int*   ei    = (const int*)d_in[1];
    const int*   batch = (const int*)d_in[2];
    const float* W_t   = (const float*)d_in[3];
    const float* b_t   = (const float*)d_in[4];
    const float* bn0_g = (const float*)d_in[5];
    const float* bn0_b = (const float*)d_in[6];
    const float* W1    = (const float*)d_in[7];
    const float* b1    = (const float*)d_in[8];
    const float* W2    = (const float*)d_in[9];
    const float* b2    = (const float*)d_in[10];
    const float* bng   = (const float*)d_in[11];
    const float* bnb   = (const float*)d_in[12];
    float* out = (float*)d_out;

    const size_t NM = (size_t)N_NODES * NHID;
    const size_t need_bytes =
        4 * 128 * sizeof(float) +
        2 * NM * sizeof(__half) +               // y, z
        (size_t)((N_GRAPHS + 1) + (N_NODES + 1) + N_EDGES + N_EDGES +
                 NBLK1 * NBUCK + (NBUCK + 1)) * sizeof(int);
    if (ws_size < need_bytes) return;

    float* stats = (float*)d_ws;               // 4 stages x 128
    __half* y    = (__half*)(stats + 4 * 128); // NM
    __half* z    = y + NM;                     // NM
    int* offs      = (int*)(z + NM);
    int* row_start = offs + N_GRAPHS + 1;
    int* esrc      = row_start + N_NODES + 1;
    int* stage     = esrc + N_EDGES;
    int* cnt       = stage + N_EDGES;
    int* bbase     = cnt + NBLK1 * NBUCK;

    const int* src = ei;
    const int* dst = ei + N_EDGES;

    // --- setup: zero, offsets, atomic-free binned CSR build ---
    k_zero<<<(N_GRAPHS * NHID + 255) / 256, 256, 0, stream>>>(stats, out);
    k_offs<<<1, 128, 0, stream>>>(batch, offs);
    k_bincount<<<NBLK1, 256, 0, stream>>>(dst, cnt);
    k_binscan<<<1, 256, 0, stream>>>(cnt, bbase, row_start);
    k_binstage<<<NBLK1, 256, 0, stream>>>(src, dst, cnt, bbase, stage);
    k_binbuild<<<NBUCK, 256, 0, stream>>>(stage, bbase, row_start, esrc);

    // --- transform: y0 = x @ W_t + b_t (stats stage 0), BN folded downstream
    k_xform<<<(N_NODES + 63) / 64, 256, 0, stream>>>(x, W_t, b_t, y, stats, N_NODES);
    k_pool<<<64 * POOL_SLICES, 256, 0, stream>>>(y, offs, stats, bn0_g, bn0_b, out);

    // --- GIN layers ---
    for (int i = 0; i < NLAYER; ++i) {
        const float* sg = (i == 0) ? bn0_g : bng + (i - 1) * NHID;
        const float* sb = (i == 0) ? bn0_b : bnb + (i - 1) * NHID;
        k_agg<<<(N_NODES * 32 + 255) / 256, 256, 0, stream>>>(
            y, row_start, esrc, stats + i * 128, sg, sb, z);
        k_layer<<<(N_NODES + 63) / 64, 256, 0, stream>>>(
            z, W1 + i * NHID * NHID, b1 + i * NHID, W2 + i * NHID * NHID,
            b2 + i * NHID, y, stats + (1 + i) * 128, N_NODES);
        k_pool<<<64 * POOL_SLICES, 256, 0, stream>>>(y, offs, stats + (1 + i) * 128,
                                                     bng + i * NHID, bnb + i * NHID, out);
    }
}